// Round 1
// baseline (1316.218 us; speedup 1.0000x reference)
//
#include <hip/hip_runtime.h>
#include <stdint.h>

#define DICT   24576
#define BLOCK  512
#define NV     12            // float4 loads per thread: DICT / BLOCK / 4
#define NB1    512           // pass-1 buckets: key32 bits [31:23] (sign+exponent)
#define NB2    128           // pass-2 buckets: key16 bits [6:0]
#define TIECAP 128

// order-preserving float -> uint32 key (ascending)
__device__ __forceinline__ uint32_t f2key(float f) {
    uint32_t u = __float_as_uint(f);
    return (u & 0x80000000u) ? ~u : (u | 0x80000000u);
}

// Executed by wave 0 (tid<64). Picks the bucket containing the r-th largest
// element (buckets ascending in key order), via per-lane segment sums and a
// 64-lane suffix scan. Writes bucket -> *s_b, remaining rank -> *s_rr.
template<int NB>
__device__ __forceinline__ void pick_bucket(const uint32_t* hist,
                                            uint32_t* s_b, uint32_t* s_rr,
                                            uint32_t r, int tid) {
    constexpr int PER_SEG = NB / 64;
    if (tid < 64) {
        uint32_t segsum = 0;
        #pragma unroll
        for (int i = 0; i < PER_SEG; ++i) {
            // rotate reads so lanes don't collide on banks
            int idx = tid * PER_SEG + ((i + tid) & (PER_SEG - 1));
            segsum += hist[idx];
        }
        // inclusive suffix sum across 64 lanes
        uint32_t S = segsum;
        #pragma unroll
        for (int off = 1; off < 64; off <<= 1) {
            uint32_t v = __shfl_down(S, off, 64);
            if (tid + off < 64) S += v;
        }
        uint32_t A = S - segsum;             // strictly above this segment
        bool cross = (A < r) && (S >= r);    // exactly one lane true
        unsigned long long m = __ballot(cross);
        int seg = __ffsll(m) - 1;
        uint32_t aboveSeg = __shfl(A, seg, 64);
        // resolve within the crossing segment (PER_SEG buckets on lanes 0..)
        uint32_t h = 0;
        if (tid < PER_SEG) h = hist[seg * PER_SEG + tid];
        uint32_t S2 = h;
        #pragma unroll
        for (int off = 1; off < PER_SEG; off <<= 1) {
            uint32_t v = __shfl_down(S2, off, 64);
            if (tid + off < PER_SEG) S2 += v;
        }
        uint32_t A2 = aboveSeg + (S2 - h);   // strictly above bucket
        if (tid < PER_SEG && A2 < r && A2 + h >= r) {
            *s_b  = (uint32_t)(seg * PER_SEG + tid);
            *s_rr = r - A2;
        }
    }
}

// Design: 512-thread blocks (3 blocks/CU, LDS 51.5KB, VGPR target <=80 via
// launch_bounds(512,6)) so barrier idle in one block overlaps with the other
// two blocks' memory phases. Selection runs on 16-bit truncated keys staged
// in LDS (2 passes: 9 exponent bits, then 7 mantissa bits); the resulting
// 16-bit threshold's tie class (expected ~6 elems for N(0,1)) is resolved
// exactly with full 32-bit keys + stable index rank. Output phase re-reads
// the row (L3-hot: concurrent working set ~75MB < 256MB Infinity Cache).
__global__ __launch_bounds__(BLOCK, 6) void topk_kernel(const float* __restrict__ z,
                                                        const int* __restrict__ kp,
                                                        float* __restrict__ out) {
    __shared__ __align__(8) uint16_t k16[DICT];   // 49152 B
    __shared__ uint32_t hist1[NB1];               // 2048 B
    __shared__ uint32_t hist2[NB2];               //  512 B
    __shared__ uint32_t tieKey[TIECAP];           //  512 B
    __shared__ uint32_t tieIdx[TIECAP];           //  512 B
    __shared__ uint32_t s_b, s_r, tieCount;

    const int tid = threadIdx.x;
    const int row = blockIdx.x;
    const uint32_t k = (uint32_t)kp[0];

    const float4* zr = (const float4*)(z + (size_t)row * DICT);
    float4* outr = (float4*)(out + (size_t)row * DICT);

    // 0) zero histograms / counters
    if (tid < NB1) hist1[tid] = 0;
    if (tid < NB2) hist2[tid] = 0;
    if (tid == 0) tieCount = 0;
    __syncthreads();

    // A) stream the row once: pack 16-bit keys to LDS + 9-bit histogram
    #pragma unroll
    for (int j = 0; j < NV; ++j) {
        float4 v = zr[j * BLOCK + tid];
        uint32_t k0 = f2key(v.x), k1 = f2key(v.y);
        uint32_t k2 = f2key(v.z), k3 = f2key(v.w);
        uint32_t p0 = (k0 >> 16) | (k1 & 0xFFFF0000u);
        uint32_t p1 = (k2 >> 16) | (k3 & 0xFFFF0000u);
        *(uint2*)&k16[j * (BLOCK * 4) + tid * 4] = make_uint2(p0, p1);
        atomicAdd(&hist1[k0 >> 23], 1u);
        atomicAdd(&hist1[k1 >> 23], 1u);
        atomicAdd(&hist1[k2 >> 23], 1u);
        atomicAdd(&hist1[k3 >> 23], 1u);
    }
    __syncthreads();

    // B) pick 9-bit bucket containing the k-th largest
    pick_bucket<NB1>(hist1, &s_b, &s_r, k, tid);
    __syncthreads();
    const uint32_t b9 = s_b;
    const uint32_t r1 = s_r;

    // C) pass 2: low 7 bits of key16, only elements in bucket b9
    #pragma unroll
    for (int j = 0; j < NV; ++j) {
        uint2 pk = *(const uint2*)&k16[j * (BLOCK * 4) + tid * 4];
        uint32_t e[4] = { pk.x & 0xFFFFu, pk.x >> 16, pk.y & 0xFFFFu, pk.y >> 16 };
        #pragma unroll
        for (int c = 0; c < 4; ++c)
            if ((e[c] >> 7) == b9) atomicAdd(&hist2[e[c] & (NB2 - 1)], 1u);
    }
    __syncthreads();
    pick_bucket<NB2>(hist2, &s_b, &s_r, r1, tid);
    __syncthreads();
    const uint32_t p16 = (b9 << 7) | s_b;   // 16-bit threshold prefix
    const uint32_t rr  = s_r;               // how many of the tie class to keep

    // D) collect tie class (key16 == p16): gathered reload for exact 32-bit keys
    #pragma unroll
    for (int j = 0; j < NV; ++j) {
        uint2 pk = *(const uint2*)&k16[j * (BLOCK * 4) + tid * 4];
        uint32_t e[4] = { pk.x & 0xFFFFu, pk.x >> 16, pk.y & 0xFFFFu, pk.y >> 16 };
        #pragma unroll
        for (int c = 0; c < 4; ++c) {
            if (e[c] == p16) {
                uint32_t gi = (uint32_t)(j * (BLOCK * 4) + tid * 4 + c);
                float v = ((const float*)zr)[gi];
                uint32_t slot = atomicAdd(&tieCount, 1u);
                if (slot < TIECAP) { tieKey[slot] = f2key(v); tieIdx[slot] = gi; }
            }
        }
    }
    __syncthreads();
    const uint32_t ec = tieCount < TIECAP ? tieCount : TIECAP;

    // rank ties by (full key desc, index asc); mark non-kept with sentinel
    bool keep = false;
    if (tid < (int)ec) {
        uint32_t mk = tieKey[tid], mi = tieIdx[tid];
        uint32_t rank = 0;
        for (uint32_t i2 = 0; i2 < ec; ++i2) {
            uint32_t ok = tieKey[i2], oi = tieIdx[i2];
            rank += (ok > mk || (ok == mk && oi < mi)) ? 1u : 0u;
        }
        keep = (rank < rr);
    }
    __syncthreads();
    if (tid < (int)ec && !keep) tieIdx[tid] = 0xFFFFFFFFu;
    __syncthreads();

    // E) write: re-read row (L3-hot), threshold in key16 space, ties via list
    #pragma unroll
    for (int j = 0; j < NV; ++j) {
        float4 v = zr[j * BLOCK + tid];
        float in[4] = { v.x, v.y, v.z, v.w };
        float o[4];
        #pragma unroll
        for (int c = 0; c < 4; ++c) {
            uint32_t kk = f2key(in[c]);
            uint32_t kv = kk >> 16;
            float val = 0.0f;
            if (kv > p16) {
                val = in[c];
            } else if (kv == p16) {
                uint32_t gi = (uint32_t)(j * (BLOCK * 4) + tid * 4 + c);
                for (uint32_t i2 = 0; i2 < ec; ++i2)
                    if (tieIdx[i2] == gi) { val = in[c]; break; }
            }
            o[c] = val;
        }
        float4 ov; ov.x = o[0]; ov.y = o[1]; ov.z = o[2]; ov.w = o[3];
        outr[j * BLOCK + tid] = ov;
    }
}

extern "C" void kernel_launch(void* const* d_in, const int* in_sizes, int n_in,
                              void* d_out, int out_size, void* d_ws, size_t ws_size,
                              hipStream_t stream) {
    const float* z = (const float*)d_in[0];
    const int*   kp = (const int*)d_in[1];
    float* out = (float*)d_out;
    const int batch = in_sizes[0] / DICT;
    topk_kernel<<<dim3(batch), dim3(BLOCK), 0, stream>>>(z, kp, out);
}